// Round 14
// baseline (577.179 us; speedup 1.0000x reference)
//
#include <hip/hip_runtime.h>
#include <hip/hip_fp16.h>
#include <stdint.h>

#define NTOK 8192
#define DDIM 1024
#define HDIM 4096
#define NEXP 8
#define CAP  3072
#define BK 32

typedef unsigned short u16;
typedef __attribute__((ext_vector_type(8))) _Float16 f16x8;
typedef __attribute__((ext_vector_type(4))) float f32x4;

__device__ __forceinline__ void gload16(const void* g, u16* l) {
  __builtin_amdgcn_global_load_lds(
      (const __attribute__((address_space(1))) void*)g,
      (__attribute__((address_space(3))) void*)l, 16, 0, 0);
}

// balanced + XCD-local decode over ACTIVE 256-row tiles.
// order: e-major, nt-major, rt-minor (B-panel reuse by consecutive blocks).
__device__ __forceinline__ bool decode256(
    const int* __restrict__ counts, int NT, int bid,
    int& e, int& rt, int& nt)
{
  int me[NEXP], offp[NEXP];
  int Wm = 0;
  #pragma unroll
  for (int k = 0; k < NEXP; ++k) {
    int c = min(counts[k], CAP);
    me[k] = (c + 255) >> 8;
    offp[k] = Wm;
    Wm += me[k];
  }
  const int WT = Wm * NT;
  if (bid >= WT) return false;
  const int q = WT >> 3, r = WT & 7, xcd = bid & 7;
  int w = (xcd < r ? xcd * (q + 1) : r * (q + 1) + (xcd - r) * q) + (bid >> 3);
  e = 0;
  #pragma unroll
  for (int k = 1; k < NEXP; ++k) if (w >= offp[k] * NT) e = k;
  const int local = w - offp[e] * NT;
  nt = local / me[e];
  rt = local - nt * me[e];
  return true;
}

// ---------------- per-expert transpose + convert: in [R][Cn] f32 -> out [Cn][R] fp16 ----------------
__global__ void cvt_t_kernel(const float* __restrict__ in, u16* __restrict__ out,
                             int R, int Cn) {
  __shared__ float t[64][65];
  int e = blockIdx.z;
  const float* ip = in + (size_t)e * R * Cn;
  size_t ob = (size_t)e * R * Cn;
  int c0 = blockIdx.x * 64, r0 = blockIdx.y * 64;
  int tc = threadIdx.x & 63, tr = threadIdx.x >> 6;
  #pragma unroll
  for (int i = 0; i < 16; ++i) {
    int r = tr + 4 * i;
    t[r][tc] = ip[(size_t)(r0 + r) * Cn + (c0 + tc)];
  }
  __syncthreads();
  const int u = threadIdx.x & 31, v = threadIdx.x >> 5;
  #pragma unroll
  for (int i = 0; i < 8; ++i) {
    int rr = v + 8 * i;
    union { __half h; u16 q; } a, b;
    a.h = __float2half(t[2 * u][rr]);
    b.h = __float2half(t[2 * u + 1][rr]);
    ushort2 pr; pr.x = a.q; pr.y = b.q;
    *(ushort2*)(out + ob + (size_t)(c0 + rr) * R + r0 + 2 * u) = pr;
  }
}

// ---------------- router: fp64 logits -> top2 gates; also emits xh = fp16(x), vectorized ----------------
__global__ void router_kernel(const float* __restrict__ x, const float* __restrict__ wr,
                              int* __restrict__ eidx, float* __restrict__ gwt,
                              u16* __restrict__ xh) {
  int wid = threadIdx.x >> 6, lane = threadIdx.x & 63;
  int n = blockIdx.x * 4 + wid;
  if (n >= NTOK) return;
  const float* xp = x + (size_t)n * DDIM;
  u16* xo = xh + (size_t)n * DDIM;
  double s[NEXP];
  #pragma unroll
  for (int e = 0; e < NEXP; ++e) s[e] = 0.0;
  for (int d0 = lane * 4; d0 < DDIM; d0 += 256) {
    float4 v = *(const float4*)(xp + d0);
    ushort4 o;
    union { __half h; u16 q; } c;
    c.h = __float2half(v.x); o.x = c.q;
    c.h = __float2half(v.y); o.y = c.q;
    c.h = __float2half(v.z); o.z = c.q;
    c.h = __float2half(v.w); o.w = c.q;
    *(ushort4*)(xo + d0) = o;
    const float vv[4] = {v.x, v.y, v.z, v.w};
    #pragma unroll
    for (int q = 0; q < 4; ++q) {
      double xv = (double)vv[q];
      #pragma unroll
      for (int e = 0; e < NEXP; ++e) s[e] += xv * (double)wr[(d0 + q) * NEXP + e];
    }
  }
  #pragma unroll
  for (int off = 32; off > 0; off >>= 1) {
    #pragma unroll
    for (int e = 0; e < NEXP; ++e) s[e] += __shfl_xor(s[e], off);
  }
  if (lane == 0) {
    int i0 = 0;
    #pragma unroll
    for (int e = 1; e < NEXP; ++e) if (s[e] > s[i0]) i0 = e;
    int i1 = (i0 == 0) ? 1 : 0;
    #pragma unroll
    for (int e = 0; e < NEXP; ++e) if (e != i0 && s[e] > s[i1]) i1 = e;
    double p1 = exp(s[i1] - s[i0]);
    double g0 = 1.0 / (1.0 + p1);
    double g1 = p1 / (1.0 + p1);
    eidx[n * 2]     = i0;
    eidx[n * 2 + 1] = i1;
    gwt[n * 2]     = (float)g0;
    gwt[n * 2 + 1] = (float)g1;
  }
}

// ---------------- deterministic slot assignment in (token, slot) pair order ----------------
// also emits inverse map tok2slot[n*2+k] = e*CAP+pos (or -1 if dropped)
__global__ __launch_bounds__(256) void assign_kernel(
    const int* __restrict__ eidx, const float* __restrict__ gwt,
    int* __restrict__ counts, int* __restrict__ row_id, int* __restrict__ t2s)
{
  __shared__ int hist[256][NEXP];
  const int t = threadIdx.x;
  const int base = t * 64;
  int loc[NEXP];
  #pragma unroll
  for (int e = 0; e < NEXP; ++e) loc[e] = 0;
  const int4* ev = (const int4*)(eidx + base);
  #pragma unroll
  for (int i = 0; i < 16; ++i) {
    int4 q4 = ev[i];
    const int es[4] = {q4.x, q4.y, q4.z, q4.w};
    #pragma unroll
    for (int c = 0; c < 4; ++c) {
      #pragma unroll
      for (int k = 0; k < NEXP; ++k) if (es[c] == k) loc[k]++;
    }
  }
  #pragma unroll
  for (int e = 0; e < NEXP; ++e) hist[t][e] = loc[e];
  __syncthreads();
  for (int s = 1; s < 256; s <<= 1) {
    int v[NEXP];
    #pragma unroll
    for (int e = 0; e < NEXP; ++e) v[e] = hist[t][e] + (t >= s ? hist[t - s][e] : 0);
    __syncthreads();
    #pragma unroll
    for (int e = 0; e < NEXP; ++e) hist[t][e] = v[e];
    __syncthreads();
  }
  int off[NEXP];
  #pragma unroll
  for (int e = 0; e < NEXP; ++e) off[e] = hist[t][e] - loc[e];
  if (t == 255) {
    #pragma unroll
    for (int e = 0; e < NEXP; ++e) counts[e] = hist[255][e];
  }
  for (int i = 0; i < 64; ++i) {
    int p = base + i;
    int e = eidx[p];
    int n = p >> 1;
    int pos = 0;
    #pragma unroll
    for (int k = 0; k < NEXP; ++k) if (e == k) { pos = off[k]; off[k] = pos + 1; }
    if (pos < CAP) {
      row_id[e * CAP + pos] = n;
      t2s[p] = e * CAP + pos;
    } else {
      t2s[p] = -1;
    }
  }
}

// ---------------- GEMM1 256x256: h = relu(x @ w1 + b1) ----------------
// 512 threads = 8 waves (2M x 4N), per-wave 128x64, acc[8][4]; 2-buf, counted vmcnt,
// 2-phase loop (32 MFMA per barrier-pair per wave), balanced XCD decode.
__global__ __launch_bounds__(512, 2) void gemm1c_kernel(
    const u16* __restrict__ xh, const u16* __restrict__ w1t,
    const float* __restrict__ b1, const int* __restrict__ counts,
    const int* __restrict__ row_id, u16* __restrict__ h)
{
  constexpr int NT = HDIM / 256;       // 16
  int e, rt, nt;
  if (!decode256(counts, NT, blockIdx.x, e, rt, nt)) return;
  const int n0 = nt * 256;

  __shared__ u16 lds[2][2][256 * BK];   // 64 KB

  const int tid = threadIdx.x;
  const int wid = tid >> 6;
  const int lane = tid & 63;

  // staging: per array 1024 16B-chunks; thread handles chunks {tid, 512+tid}
  const u16* gA[2];
  const u16* gB[2];
  int coff[2];
  #pragma unroll
  for (int i = 0; i < 2; ++i) {
    int cidx = i * 512 + tid;
    int row = cidx >> 2, cs = cidx & 3;
    int csrc = cs ^ ((row >> 1) & 3);          // bank-conflict swizzle (involution)
    int koff = csrc * 8;
    int tok = row_id[e * CAP + rt * 256 + row];
    gA[i] = xh + (size_t)tok * DDIM + koff;
    gB[i] = w1t + ((size_t)e * HDIM + (n0 + row)) * DDIM + koff;
    coff[i] = cidx * 8;
  }

#define STAGE1(buf, k0)                                             \
  {                                                                 \
    _Pragma("unroll")                                               \
    for (int i = 0; i < 2; ++i) gload16(gA[i] + (k0), &lds[buf][0][coff[i]]); \
    _Pragma("unroll")                                               \
    for (int i = 0; i < 2; ++i) gload16(gB[i] + (k0), &lds[buf][1][coff[i]]); \
  }

  f32x4 acc[8][4];
  #pragma unroll
  for (int i = 0; i < 8; ++i)
    #pragma unroll
    for (int j = 0; j < 4; ++j)
      #pragma unroll
      for (int r = 0; r < 4; ++r) acc[i][j][r] = 0.f;

  const int wm = wid >> 2, wn = wid & 3;
  const int lr = lane & 15;
  const int swz = ((lane >> 4) ^ ((lr >> 1) & 3)) * 8;
  int offA[8], offB[4];
  #pragma unroll
  for (int i = 0; i < 8; ++i) offA[i] = (wm * 128 + i * 16 + lr) * BK + swz;
  #pragma unroll
  for (int j = 0; j < 4; ++j) offB[j] = (wn * 64 + j * 16 + lr) * BK + swz;

  STAGE1(0, 0);

  const int nK = DDIM / BK;
  for (int kt = 0; kt < nK; ++kt) {
    const int cur = kt & 1;
    if (kt + 1 < nK) {
      STAGE1(cur ^ 1, (kt + 1) * BK);
      asm volatile("s_waitcnt vmcnt(4)" ::: "memory");
    } else {
      asm volatile("s_waitcnt vmcnt(0)" ::: "memory");
    }
    __builtin_amdgcn_s_barrier();
    asm volatile("" ::: "memory");
    f16x8 av[8], bv[4];
    #pragma unroll
    for (int i = 0; i < 8; ++i) av[i] = *(const f16x8*)&lds[cur][0][offA[i]];
    #pragma unroll
    for (int j = 0; j < 4; ++j) bv[j] = *(const f16x8*)&lds[cur][1][offB[j]];
    #pragma unroll
    for (int i = 0; i < 8; ++i)
      #pragma unroll
      for (int j = 0; j < 4; ++j)
        acc[i][j] = __builtin_amdgcn_mfma_f32_16x16x32_f16(av[i], bv[j], acc[i][j], 0, 0, 0);
    asm volatile("" ::: "memory");
    __builtin_amdgcn_s_barrier();
  }
#undef STAGE1

  const int colb = n0 + wn * 64 + lr;
  float bias[4];
  #pragma unroll
  for (int j = 0; j < 4; ++j) bias[j] = b1[e * HDIM + colb + j * 16];
  const size_t hbase = ((size_t)e * CAP + rt * 256 + wm * 128) * HDIM;
  #pragma unroll
  for (int i = 0; i < 8; ++i)
    #pragma unroll
    for (int r = 0; r < 4; ++r) {
      const int row = i * 16 + (lane >> 4) * 4 + r;
      #pragma unroll
      for (int j = 0; j < 4; ++j) {
        float v = acc[i][j][r] + bias[j];
        v = fmaxf(v, 0.f);
        union { __half hh; u16 u; } cv;
        cv.hh = __float2half(v);
        h[hbase + (size_t)row * HDIM + colb + j * 16] = cv.u;
      }
    }
}

// ---------------- GEMM2 256x256: eo[slot] = h @ w2 + b2 (plain f16 stores) ----------------
__global__ __launch_bounds__(512, 2) void gemm2c_kernel(
    const u16* __restrict__ h, const u16* __restrict__ w2t,
    const float* __restrict__ b2, const int* __restrict__ counts,
    u16* __restrict__ eo)
{
  constexpr int NT = DDIM / 256;       // 4
  int e, rt, nt;
  if (!decode256(counts, NT, blockIdx.x, e, rt, nt)) return;
  const int n0 = nt * 256;

  __shared__ u16 lds[2][2][256 * BK];   // 64 KB

  const int tid = threadIdx.x;
  const int wid = tid >> 6;
  const int lane = tid & 63;

  const u16* gA[2];
  const u16* gB[2];
  int coff[2];
  #pragma unroll
  for (int i = 0; i < 2; ++i) {
    int cidx = i * 512 + tid;
    int row = cidx >> 2, cs = cidx & 3;
    int csrc = cs ^ ((row >> 1) & 3);
    int koff = csrc * 8;
    gA[i] = h + ((size_t)e * CAP + rt * 256 + row) * HDIM + koff;
    gB[i] = w2t + ((size_t)e * DDIM + (n0 + row)) * HDIM + koff;
    coff[i] = cidx * 8;
  }

#define STAGE2(buf, k0)                                             \
  {                                                                 \
    _Pragma("unroll")                                               \
    for (int i = 0; i < 2; ++i) gload16(gA[i] + (k0), &lds[buf][0][coff[i]]); \
    _Pragma("unroll")                                               \
    for (int i = 0; i < 2; ++i) gload16(gB[i] + (k0), &lds[buf][1][coff[i]]); \
  }

  f32x4 acc[8][4];
  #pragma unroll
  for (int i = 0; i < 8; ++i)
    #pragma unroll
    for (int j = 0; j < 4; ++j)
      #pragma unroll
      for (int r = 0; r < 4; ++r) acc[i][j][r] = 0.f;

  const int wm = wid >> 2, wn = wid & 3;
  const int lr = lane & 15;
  const int swz = ((lane >> 4) ^ ((lr >> 1) & 3)) * 8;
  int offA[8], offB[4];
  #pragma unroll
  for (int i = 0; i < 8; ++i) offA[i] = (wm * 128 + i * 16 + lr) * BK + swz;
  #pragma unroll
  for (int j = 0; j < 4; ++j) offB[j] = (wn * 64 + j * 16 + lr) * BK + swz;

  STAGE2(0, 0);

  const int nK = HDIM / BK;
  for (int kt = 0; kt < nK; ++kt) {
    const int cur = kt & 1;
    if (kt + 1 < nK) {
      STAGE2(cur ^ 1, (kt + 1) * BK);
      asm volatile("s_waitcnt vmcnt(4)" ::: "memory");
    } else {
      asm volatile("s_waitcnt vmcnt(0)" ::: "memory");
    }
    __builtin_amdgcn_s_barrier();
    asm volatile("" ::: "memory");
    f16x8 av[8], bv[4];
    #pragma unroll
    for (int i = 0; i < 8; ++i) av[i] = *(const f16x8*)&lds[cur][0][offA[i]];
    #pragma unroll
    for (int j = 0; j < 4; ++j) bv[j] = *(const f16x8*)&lds[cur][1][offB[j]];
    #pragma unroll
    for (int i = 0; i < 8; ++i)
      #pragma unroll
      for (int j = 0; j < 4; ++j)
        acc[i][j] = __builtin_amdgcn_mfma_f32_16x16x32_f16(av[i], bv[j], acc[i][j], 0, 0, 0);
    asm volatile("" ::: "memory");
    __builtin_amdgcn_s_barrier();
  }
#undef STAGE2

  const int colb = n0 + wn * 64 + lr;
  float bias[4];
  #pragma unroll
  for (int j = 0; j < 4; ++j) bias[j] = b2[e * DDIM + colb + j * 16];
  const size_t ebase = ((size_t)e * CAP + rt * 256 + wm * 128) * DDIM;
  #pragma unroll
  for (int i = 0; i < 8; ++i)
    #pragma unroll
    for (int r = 0; r < 4; ++r) {
      const int row = i * 16 + (lane >> 4) * 4 + r;
      #pragma unroll
      for (int j = 0; j < 4; ++j) {
        float v = acc[i][j][r] + bias[j];
        union { __half hh; u16 u; } cv;
        cv.hh = __float2half(v);
        eo[ebase + (size_t)row * DDIM + colb + j * 16] = cv.u;
      }
    }
}

// ---------------- combine: y[n] = g0*eo[s0] + g1*eo[s1] ----------------
__global__ __launch_bounds__(256) void combine_kernel(
    const u16* __restrict__ eo, const int* __restrict__ t2s,
    const float* __restrict__ gwt, float* __restrict__ y)
{
  const int n = blockIdx.x;
  const int t = threadIdx.x;
  const int s0 = t2s[n * 2], s1 = t2s[n * 2 + 1];
  const float g0 = gwt[n * 2], g1 = gwt[n * 2 + 1];
  const int d0 = t * 4;
  float a0 = 0.f, a1 = 0.f, a2 = 0.f, a3 = 0.f;
  union { __half h; u16 q; } c;
  if (s0 >= 0) {
    ushort4 v = *(const ushort4*)(eo + (size_t)s0 * DDIM + d0);
    c.q = v.x; a0 += g0 * __half2float(c.h);
    c.q = v.y; a1 += g0 * __half2float(c.h);
    c.q = v.z; a2 += g0 * __half2float(c.h);
    c.q = v.w; a3 += g0 * __half2float(c.h);
  }
  if (s1 >= 0) {
    ushort4 v = *(const ushort4*)(eo + (size_t)s1 * DDIM + d0);
    c.q = v.x; a0 += g1 * __half2float(c.h);
    c.q = v.y; a1 += g1 * __half2float(c.h);
    c.q = v.z; a2 += g1 * __half2float(c.h);
    c.q = v.w; a3 += g1 * __half2float(c.h);
  }
  float4 out = {a0, a1, a2, a3};
  *(float4*)(y + (size_t)n * DDIM + d0) = out;
}

extern "C" void kernel_launch(void* const* d_in, const int* in_sizes, int n_in,
                              void* d_out, int out_size, void* d_ws, size_t ws_size,
                              hipStream_t stream)
{
  const float* x  = (const float*)d_in[0];
  const float* wr = (const float*)d_in[1];
  const float* w1 = (const float*)d_in[2];
  const float* b1 = (const float*)d_in[3];
  const float* w2 = (const float*)d_in[4];
  const float* b2 = (const float*)d_in[5];
  float* y = (float*)d_out;

  char* ws = (char*)d_ws;
  int*   counts = (int*)ws;
  int*   eidx   = (int*)(ws + 256);
  float* gwt    = (float*)(ws + 256 + NTOK * 2 * 4);
  int*   row_id = (int*)(ws + 256 + 2 * NTOK * 2 * 4);
  int*   t2s    = (int*)(ws + 256 + 2 * NTOK * 2 * 4 + NEXP * CAP * 4);
  u16*   xh     = (u16*)(ws + (1 << 20));                 // 16 MiB
  u16*   wth    = xh   + (size_t)NTOK * DDIM;             // 64 MiB (w1t, then reused for w2t)
  u16*   h      = wth  + (size_t)NEXP * DDIM * HDIM;      // 192 MiB
  u16*   eo     = h    + (size_t)NEXP * CAP * HDIM;       // 48 MiB

  hipMemsetAsync(ws, 0, 1 << 20, stream);

  router_kernel<<<NTOK / 4, 256, 0, stream>>>(x, wr, eidx, gwt, xh);
  assign_kernel<<<1, 256, 0, stream>>>(eidx, gwt, counts, row_id, t2s);
  cvt_t_kernel<<<dim3(HDIM / 64, DDIM / 64, NEXP), 256, 0, stream>>>(w1, wth, DDIM, HDIM);
  gemm1c_kernel<<<NEXP * (CAP / 256) * (HDIM / 256), 512, 0, stream>>>(
      xh, wth, b1, counts, row_id, h);
  cvt_t_kernel<<<dim3(DDIM / 64, HDIM / 64, NEXP), 256, 0, stream>>>(w2, wth, HDIM, DDIM);
  gemm2c_kernel<<<NEXP * (CAP / 256) * (DDIM / 256), 512, 0, stream>>>(
      h, wth, b2, counts, eo);
  combine_kernel<<<NTOK, 256, 0, stream>>>(eo, t2s, gwt, y);
}

// Round 15
// 537.772 us; speedup vs baseline: 1.0733x; 1.0733x over previous
//
#include <hip/hip_runtime.h>
#include <hip/hip_fp16.h>
#include <stdint.h>

#define NTOK 8192
#define DDIM 1024
#define HDIM 4096
#define NEXP 8
#define CAP  3072
#define BK 32

typedef unsigned short u16;
typedef __attribute__((ext_vector_type(8))) _Float16 f16x8;
typedef __attribute__((ext_vector_type(4))) float f32x4;

__device__ __forceinline__ void gload16(const void* g, u16* l) {
  __builtin_amdgcn_global_load_lds(
      (const __attribute__((address_space(1))) void*)g,
      (__attribute__((address_space(3))) void*)l, 16, 0, 0);
}

// balanced + XCD-local work decode over ragged active tiles.
// order: e-major, nt-major, rt-minor (m-fastest). bijective chunk swizzle over WT.
__device__ __forceinline__ bool decode_work(
    const int* __restrict__ counts, int NT, int bid,
    int& e, int& rt, int& nt)
{
  int me[NEXP], offp[NEXP];
  int Wm = 0;
  #pragma unroll
  for (int k = 0; k < NEXP; ++k) {
    int c = min(counts[k], CAP);
    me[k] = (c + 127) >> 7;
    offp[k] = Wm;
    Wm += me[k];
  }
  const int WT = Wm * NT;
  if (bid >= WT) return false;
  const int q = WT >> 3, r = WT & 7, xcd = bid & 7;
  int w = (xcd < r ? xcd * (q + 1) : r * (q + 1) + (xcd - r) * q) + (bid >> 3);
  e = 0;
  #pragma unroll
  for (int k = 1; k < NEXP; ++k) if (w >= offp[k] * NT) e = k;
  const int local = w - offp[e] * NT;
  nt = local / me[e];
  rt = local - nt * me[e];
  return true;
}

// ---------------- per-expert transpose + convert: in [R][Cn] f32 -> out [Cn][R] fp16 ----------------
__global__ void cvt_t_kernel(const float* __restrict__ in, u16* __restrict__ out,
                             int R, int Cn) {
  __shared__ float t[64][65];
  int e = blockIdx.z;
  const float* ip = in + (size_t)e * R * Cn;
  size_t ob = (size_t)e * R * Cn;
  int c0 = blockIdx.x * 64, r0 = blockIdx.y * 64;
  int tc = threadIdx.x & 63, tr = threadIdx.x >> 6;
  #pragma unroll
  for (int i = 0; i < 16; ++i) {
    int r = tr + 4 * i;
    t[r][tc] = ip[(size_t)(r0 + r) * Cn + (c0 + tc)];
  }
  __syncthreads();
  const int u = threadIdx.x & 31, v = threadIdx.x >> 5;
  #pragma unroll
  for (int i = 0; i < 8; ++i) {
    int rr = v + 8 * i;
    union { __half h; u16 q; } a, b;
    a.h = __float2half(t[2 * u][rr]);
    b.h = __float2half(t[2 * u + 1][rr]);
    ushort2 pr; pr.x = a.q; pr.y = b.q;
    *(ushort2*)(out + ob + (size_t)(c0 + rr) * R + r0 + 2 * u) = pr;
  }
}

// ---------------- router: fp64 logits -> top2 gates; also emits xh = fp16(x), vectorized ----------------
__global__ void router_kernel(const float* __restrict__ x, const float* __restrict__ wr,
                              int* __restrict__ eidx, float* __restrict__ gwt,
                              u16* __restrict__ xh) {
  int wid = threadIdx.x >> 6, lane = threadIdx.x & 63;
  int n = blockIdx.x * 4 + wid;
  if (n >= NTOK) return;
  const float* xp = x + (size_t)n * DDIM;
  u16* xo = xh + (size_t)n * DDIM;
  double s[NEXP];
  #pragma unroll
  for (int e = 0; e < NEXP; ++e) s[e] = 0.0;
  for (int d0 = lane * 4; d0 < DDIM; d0 += 256) {
    float4 v = *(const float4*)(xp + d0);
    ushort4 o;
    union { __half h; u16 q; } c;
    c.h = __float2half(v.x); o.x = c.q;
    c.h = __float2half(v.y); o.y = c.q;
    c.h = __float2half(v.z); o.z = c.q;
    c.h = __float2half(v.w); o.w = c.q;
    *(ushort4*)(xo + d0) = o;
    const float vv[4] = {v.x, v.y, v.z, v.w};
    #pragma unroll
    for (int q = 0; q < 4; ++q) {
      double xv = (double)vv[q];
      #pragma unroll
      for (int e = 0; e < NEXP; ++e) s[e] += xv * (double)wr[(d0 + q) * NEXP + e];
    }
  }
  #pragma unroll
  for (int off = 32; off > 0; off >>= 1) {
    #pragma unroll
    for (int e = 0; e < NEXP; ++e) s[e] += __shfl_xor(s[e], off);
  }
  if (lane == 0) {
    int i0 = 0;
    #pragma unroll
    for (int e = 1; e < NEXP; ++e) if (s[e] > s[i0]) i0 = e;
    int i1 = (i0 == 0) ? 1 : 0;
    #pragma unroll
    for (int e = 0; e < NEXP; ++e) if (e != i0 && s[e] > s[i1]) i1 = e;
    double p1 = exp(s[i1] - s[i0]);
    double g0 = 1.0 / (1.0 + p1);
    double g1 = p1 / (1.0 + p1);
    eidx[n * 2]     = i0;
    eidx[n * 2 + 1] = i1;
    gwt[n * 2]     = (float)g0;
    gwt[n * 2 + 1] = (float)g1;
  }
}

// ---------------- deterministic slot assignment in (token, slot) pair order ----------------
// also emits inverse map tok2slot[n*2+k] = e*CAP+pos (or -1 if dropped)
__global__ __launch_bounds__(256) void assign_kernel(
    const int* __restrict__ eidx, const float* __restrict__ gwt,
    int* __restrict__ counts, int* __restrict__ row_id, int* __restrict__ t2s)
{
  __shared__ int hist[256][NEXP];
  const int t = threadIdx.x;
  const int base = t * 64;
  int loc[NEXP];
  #pragma unroll
  for (int e = 0; e < NEXP; ++e) loc[e] = 0;
  const int4* ev = (const int4*)(eidx + base);
  #pragma unroll
  for (int i = 0; i < 16; ++i) {
    int4 q4 = ev[i];
    const int es[4] = {q4.x, q4.y, q4.z, q4.w};
    #pragma unroll
    for (int c = 0; c < 4; ++c) {
      #pragma unroll
      for (int k = 0; k < NEXP; ++k) if (es[c] == k) loc[k]++;
    }
  }
  #pragma unroll
  for (int e = 0; e < NEXP; ++e) hist[t][e] = loc[e];
  __syncthreads();
  for (int s = 1; s < 256; s <<= 1) {
    int v[NEXP];
    #pragma unroll
    for (int e = 0; e < NEXP; ++e) v[e] = hist[t][e] + (t >= s ? hist[t - s][e] : 0);
    __syncthreads();
    #pragma unroll
    for (int e = 0; e < NEXP; ++e) hist[t][e] = v[e];
    __syncthreads();
  }
  int off[NEXP];
  #pragma unroll
  for (int e = 0; e < NEXP; ++e) off[e] = hist[t][e] - loc[e];
  if (t == 255) {
    #pragma unroll
    for (int e = 0; e < NEXP; ++e) counts[e] = hist[255][e];
  }
  for (int i = 0; i < 64; ++i) {
    int p = base + i;
    int e = eidx[p];
    int n = p >> 1;
    int pos = 0;
    #pragma unroll
    for (int k = 0; k < NEXP; ++k) if (e == k) { pos = off[k]; off[k] = pos + 1; }
    if (pos < CAP) {
      row_id[e * CAP + pos] = n;
      t2s[p] = e * CAP + pos;
    } else {
      t2s[p] = -1;
    }
  }
}

// ---------------- GEMM1: h = relu(x @ w1 + b1) ----------------
// 3-buf LDS, single barrier per K-step (stage-at-end), counted vmcnt, balanced XCD decode
__global__ __launch_bounds__(256, 3) void gemm1b_kernel(
    const u16* __restrict__ xh, const u16* __restrict__ w1t,
    const float* __restrict__ b1, const int* __restrict__ counts,
    const int* __restrict__ row_id, u16* __restrict__ h)
{
  constexpr int NT = HDIM / 128;       // 32
  int e, rt, nt;
  if (!decode_work(counts, NT, blockIdx.x, e, rt, nt)) return;
  const int n0 = nt * 128;

  __shared__ u16 lds[3][2][128 * BK];   // 48 KB

  const int tid = threadIdx.x;
  const int wid = tid >> 6;
  const int lane = tid & 63;

  const u16* gA[2];
  const u16* gB[2];
  int coff[2];
  #pragma unroll
  for (int i = 0; i < 2; ++i) {
    int cidx = i * 256 + tid;
    int row = cidx >> 2, cs = cidx & 3;
    int csrc = cs ^ ((row >> 1) & 3);          // bank-conflict swizzle (involution)
    int koff = csrc * 8;
    int tok = row_id[e * CAP + rt * 128 + row];
    gA[i] = xh + (size_t)tok * DDIM + koff;
    gB[i] = w1t + ((size_t)e * HDIM + (n0 + row)) * DDIM + koff;
    coff[i] = cidx * 8;
  }

#define STAGE1(buf, k0)                                             \
  {                                                                 \
    _Pragma("unroll")                                               \
    for (int i = 0; i < 2; ++i) gload16(gA[i] + (k0), &lds[buf][0][coff[i]]); \
    _Pragma("unroll")                                               \
    for (int i = 0; i < 2; ++i) gload16(gB[i] + (k0), &lds[buf][1][coff[i]]); \
  }

  f32x4 acc[4][4];
  #pragma unroll
  for (int i = 0; i < 4; ++i)
    #pragma unroll
    for (int j = 0; j < 4; ++j)
      #pragma unroll
      for (int r = 0; r < 4; ++r) acc[i][j][r] = 0.f;

  const int wm = wid >> 1, wn = wid & 1;
  const int lr = lane & 15;
  const int swz = ((lane >> 4) ^ ((lr >> 1) & 3)) * 8;
  int offA[4], offB[4];
  #pragma unroll
  for (int i = 0; i < 4; ++i) offA[i] = (wm * 64 + i * 16 + lr) * BK + swz;
  #pragma unroll
  for (int j = 0; j < 4; ++j) offB[j] = (wn * 64 + j * 16 + lr) * BK + swz;

  STAGE1(0, 0);
  STAGE1(1, BK);

  const int nK = DDIM / BK;
  for (int kt = 0; kt < nK; ++kt) {
    const int cur = kt % 3;
    if (kt + 1 < nK) {
      asm volatile("s_waitcnt vmcnt(4)" ::: "memory");
    } else {
      asm volatile("s_waitcnt vmcnt(0)" ::: "memory");
    }
    __builtin_amdgcn_s_barrier();
    asm volatile("" ::: "memory");
    f16x8 av[4], bv[4];
    #pragma unroll
    for (int i = 0; i < 4; ++i) av[i] = *(const f16x8*)&lds[cur][0][offA[i]];
    #pragma unroll
    for (int j = 0; j < 4; ++j) bv[j] = *(const f16x8*)&lds[cur][1][offB[j]];
    #pragma unroll
    for (int i = 0; i < 4; ++i)
      #pragma unroll
      for (int j = 0; j < 4; ++j)
        acc[i][j] = __builtin_amdgcn_mfma_f32_16x16x32_f16(av[i], bv[j], acc[i][j], 0, 0, 0);
    asm volatile("" ::: "memory");
    if (kt + 2 < nK) STAGE1((kt + 2) % 3, (kt + 2) * BK);
  }
#undef STAGE1

  const int colb = n0 + wn * 64 + lr;
  float bias[4];
  #pragma unroll
  for (int j = 0; j < 4; ++j) bias[j] = b1[e * HDIM + colb + j * 16];
  const size_t hbase = ((size_t)e * CAP + rt * 128 + wm * 64) * HDIM;
  #pragma unroll
  for (int i = 0; i < 4; ++i)
    #pragma unroll
    for (int r = 0; r < 4; ++r) {
      const int row = i * 16 + (lane >> 4) * 4 + r;
      #pragma unroll
      for (int j = 0; j < 4; ++j) {
        float v = acc[i][j][r] + bias[j];
        v = fmaxf(v, 0.f);
        union { __half hh; u16 u; } cv;
        cv.hh = __float2half(v);
        h[hbase + (size_t)row * HDIM + colb + j * 16] = cv.u;
      }
    }
}

// ---------------- GEMM2: eo[slot] = h @ w2 + b2 (plain f16 stores, no atomics) ----------------
__global__ __launch_bounds__(256, 3) void gemm2b_kernel(
    const u16* __restrict__ h, const u16* __restrict__ w2t,
    const float* __restrict__ b2, const int* __restrict__ counts,
    u16* __restrict__ eo)
{
  constexpr int NT = DDIM / 128;       // 8
  int e, rt, nt;
  if (!decode_work(counts, NT, blockIdx.x, e, rt, nt)) return;
  const int n0 = nt * 128;

  __shared__ u16 lds[3][2][128 * BK];   // 48 KB

  const int tid = threadIdx.x;
  const int wid = tid >> 6;
  const int lane = tid & 63;

  const u16* gA[2];
  const u16* gB[2];
  int coff[2];
  #pragma unroll
  for (int i = 0; i < 2; ++i) {
    int cidx = i * 256 + tid;
    int row = cidx >> 2, cs = cidx & 3;
    int csrc = cs ^ ((row >> 1) & 3);
    int koff = csrc * 8;
    gA[i] = h + ((size_t)e * CAP + rt * 128 + row) * HDIM + koff;
    gB[i] = w2t + ((size_t)e * DDIM + (n0 + row)) * HDIM + koff;
    coff[i] = cidx * 8;
  }

#define STAGE2(buf, k0)                                             \
  {                                                                 \
    _Pragma("unroll")                                               \
    for (int i = 0; i < 2; ++i) gload16(gA[i] + (k0), &lds[buf][0][coff[i]]); \
    _Pragma("unroll")                                               \
    for (int i = 0; i < 2; ++i) gload16(gB[i] + (k0), &lds[buf][1][coff[i]]); \
  }

  f32x4 acc[4][4];
  #pragma unroll
  for (int i = 0; i < 4; ++i)
    #pragma unroll
    for (int j = 0; j < 4; ++j)
      #pragma unroll
      for (int r = 0; r < 4; ++r) acc[i][j][r] = 0.f;

  const int wm = wid >> 1, wn = wid & 1;
  const int lr = lane & 15;
  const int swz = ((lane >> 4) ^ ((lr >> 1) & 3)) * 8;
  int offA[4], offB[4];
  #pragma unroll
  for (int i = 0; i < 4; ++i) offA[i] = (wm * 64 + i * 16 + lr) * BK + swz;
  #pragma unroll
  for (int j = 0; j < 4; ++j) offB[j] = (wn * 64 + j * 16 + lr) * BK + swz;

  STAGE2(0, 0);
  STAGE2(1, BK);

  const int nK = HDIM / BK;
  for (int kt = 0; kt < nK; ++kt) {
    const int cur = kt % 3;
    if (kt + 1 < nK) {
      asm volatile("s_waitcnt vmcnt(4)" ::: "memory");
    } else {
      asm volatile("s_waitcnt vmcnt(0)" ::: "memory");
    }
    __builtin_amdgcn_s_barrier();
    asm volatile("" ::: "memory");
    f16x8 av[4], bv[4];
    #pragma unroll
    for (int i = 0; i < 4; ++i) av[i] = *(const f16x8*)&lds[cur][0][offA[i]];
    #pragma unroll
    for (int j = 0; j < 4; ++j) bv[j] = *(const f16x8*)&lds[cur][1][offB[j]];
    #pragma unroll
    for (int i = 0; i < 4; ++i)
      #pragma unroll
      for (int j = 0; j < 4; ++j)
        acc[i][j] = __builtin_amdgcn_mfma_f32_16x16x32_f16(av[i], bv[j], acc[i][j], 0, 0, 0);
    asm volatile("" ::: "memory");
    if (kt + 2 < nK) STAGE2((kt + 2) % 3, (kt + 2) * BK);
  }
#undef STAGE2

  const int colb = n0 + wn * 64 + lr;
  float bias[4];
  #pragma unroll
  for (int j = 0; j < 4; ++j) bias[j] = b2[e * DDIM + colb + j * 16];
  const size_t ebase = ((size_t)e * CAP + rt * 128 + wm * 64) * DDIM;
  #pragma unroll
  for (int i = 0; i < 4; ++i)
    #pragma unroll
    for (int r = 0; r < 4; ++r) {
      const int row = i * 16 + (lane >> 4) * 4 + r;
      #pragma unroll
      for (int j = 0; j < 4; ++j) {
        float v = acc[i][j][r] + bias[j];
        union { __half hh; u16 u; } cv;
        cv.hh = __float2half(v);
        eo[ebase + (size_t)row * DDIM + colb + j * 16] = cv.u;
      }
    }
}

// ---------------- combine: y[n] = g0*eo[s0] + g1*eo[s1] ----------------
__global__ __launch_bounds__(256) void combine_kernel(
    const u16* __restrict__ eo, const int* __restrict__ t2s,
    const float* __restrict__ gwt, float* __restrict__ y)
{
  const int n = blockIdx.x;
  const int t = threadIdx.x;
  const int s0 = t2s[n * 2], s1 = t2s[n * 2 + 1];
  const float g0 = gwt[n * 2], g1 = gwt[n * 2 + 1];
  const int d0 = t * 4;
  float a0 = 0.f, a1 = 0.f, a2 = 0.f, a3 = 0.f;
  union { __half h; u16 q; } c;
  if (s0 >= 0) {
    ushort4 v = *(const ushort4*)(eo + (size_t)s0 * DDIM + d0);
    c.q = v.x; a0 += g0 * __half2float(c.h);
    c.q = v.y; a1 += g0 * __half2float(c.h);
    c.q = v.z; a2 += g0 * __half2float(c.h);
    c.q = v.w; a3 += g0 * __half2float(c.h);
  }
  if (s1 >= 0) {
    ushort4 v = *(const ushort4*)(eo + (size_t)s1 * DDIM + d0);
    c.q = v.x; a0 += g1 * __half2float(c.h);
    c.q = v.y; a1 += g1 * __half2float(c.h);
    c.q = v.z; a2 += g1 * __half2float(c.h);
    c.q = v.w; a3 += g1 * __half2float(c.h);
  }
  float4 out = {a0, a1, a2, a3};
  *(float4*)(y + (size_t)n * DDIM + d0) = out;
}

extern "C" void kernel_launch(void* const* d_in, const int* in_sizes, int n_in,
                              void* d_out, int out_size, void* d_ws, size_t ws_size,
                              hipStream_t stream)
{
  const float* x  = (const float*)d_in[0];
  const float* wr = (const float*)d_in[1];
  const float* w1 = (const float*)d_in[2];
  const float* b1 = (const float*)d_in[3];
  const float* w2 = (const float*)d_in[4];
  const float* b2 = (const float*)d_in[5];
  float* y = (float*)d_out;

  char* ws = (char*)d_ws;
  int*   counts = (int*)ws;
  int*   eidx   = (int*)(ws + 256);
  float* gwt    = (float*)(ws + 256 + NTOK * 2 * 4);
  int*   row_id = (int*)(ws + 256 + 2 * NTOK * 2 * 4);
  int*   t2s    = (int*)(ws + 256 + 2 * NTOK * 2 * 4 + NEXP * CAP * 4);
  u16*   xh     = (u16*)(ws + (1 << 20));                 // 16 MiB
  u16*   wth    = xh   + (size_t)NTOK * DDIM;             // 64 MiB (w1t, then reused for w2t)
  u16*   h      = wth  + (size_t)NEXP * DDIM * HDIM;      // 192 MiB
  u16*   eo     = h    + (size_t)NEXP * CAP * HDIM;       // 48 MiB

  hipMemsetAsync(ws, 0, 1 << 20, stream);

  router_kernel<<<NTOK / 4, 256, 0, stream>>>(x, wr, eidx, gwt, xh);
  assign_kernel<<<1, 256, 0, stream>>>(eidx, gwt, counts, row_id, t2s);
  cvt_t_kernel<<<dim3(HDIM / 64, DDIM / 64, NEXP), 256, 0, stream>>>(w1, wth, DDIM, HDIM);
  gemm1b_kernel<<<NEXP * (CAP / 128) * (HDIM / 128), 256, 0, stream>>>(
      xh, wth, b1, counts, row_id, h);
  cvt_t_kernel<<<dim3(DDIM / 64, HDIM / 64, NEXP), 256, 0, stream>>>(w2, wth, HDIM, DDIM);
  gemm2b_kernel<<<NEXP * (CAP / 128) * (DDIM / 128), 256, 0, stream>>>(
      h, wth, b2, counts, eo);
  combine_kernel<<<NTOK, 256, 0, stream>>>(eo, t2s, gwt, y);
}